// Round 9
// baseline (175.752 us; speedup 1.0000x reference)
//
#include <hip/hip_runtime.h>
#include <hip/hip_bf16.h>

#define D_DIM 1024
#define S_DIM 2048
#define B_DIM 4
#define KTAPS 16

typedef short bf16x8 __attribute__((ext_vector_type(8)));
typedef float f32x4 __attribute__((ext_vector_type(4)));

static __device__ __forceinline__ short f2bs(float f) {
  __hip_bfloat16 h = __float2bfloat16(f);
  return *reinterpret_cast<short*>(&h);
}
static __device__ __forceinline__ float bs2f(short s) {
  unsigned int u = ((unsigned int)(unsigned short)s) << 16;
  return __builtin_bit_cast(float, u);
}

// Fragment-order flat index (both A and B operands, 16-row panels):
//   f(p, k0, lane, j) = ((p*32 + k0)*64 + lane)*8 + j
//   row (m or n) = p*16 + (lane&15),  k = k0*32 + (lane>>4)*8 + j
// A wave's fragment load is then ONE coalesced 16B/lane global load.

// ---------------------------------------------------------------------------
// Kernel 1 (merged setup): blocks [0,4096) write Wb in B-FRAGMENT ORDER;
// blocks [4096,4160) compute impulse response g_k[d] = C_d.A_d^k.B_d.
// ---------------------------------------------------------------------------
__global__ void setup_kernel(const float* __restrict__ W, __hip_bfloat16* __restrict__ Wbf,
                             const float* __restrict__ A, const float* __restrict__ Bm,
                             const float* __restrict__ Cm, const float* __restrict__ Dm,
                             float* __restrict__ gT) {
  if (blockIdx.x < 4096) {
    const int f    = blockIdx.x * 256 + threadIdx.x;
    const int p    = f >> 14;            // n-panel (0..63)
    const int k0   = (f >> 9) & 31;      // 32-wide k block
    const int lane = (f >> 3) & 63;
    const int j    = f & 7;
    const int n    = p * 16 + (lane & 15);
    const int k    = k0 * 32 + (lane >> 4) * 8 + j;
    Wbf[f] = __float2bfloat16(W[n * D_DIM + k]);
    return;
  }
  const int gb   = blockIdx.x - 4096;  // 0..63
  const int wid  = threadIdx.x >> 6;   // 0..3
  const int lane = threadIdx.x & 63;
  const int sub  = lane >> 4;          // 0..3 (channel within wave)
  const int n    = lane & 15;          // state index
  const int d    = gb * 16 + wid * 4 + sub;
  float Ar[16];
#pragma unroll
  for (int m = 0; m < 16; ++m) Ar[m] = A[d * 256 + n * 16 + m];
  float v = Bm[d * 16 + n];
  const float c   = Cm[d * 16 + n];
  const float dmv = Dm[d];
  const int base  = sub << 4;
  for (int k = 0; k < KTAPS; ++k) {
    float dot = c * v;
    dot += __shfl_xor(dot, 1);
    dot += __shfl_xor(dot, 2);
    dot += __shfl_xor(dot, 4);
    dot += __shfl_xor(dot, 8);
    if (k == 0) dot += dmv;            // fold the D x_t skip term into tap 0
    if (n == 0) gT[k * D_DIM + d] = dot;
    float nv = 0.f;
#pragma unroll
    for (int m = 0; m < 16; ++m) nv = fmaf(Ar[m], __shfl(v, base + m), nv);
    v = nv;
  }
}

// ---------------------------------------------------------------------------
// Kernel 2: depthwise causal conv, 16 taps, y emitted in bf16 (row-major).
// Block = (b, 64-row chunk, 256-channel group), 512 blocks.
// ---------------------------------------------------------------------------
__global__ __launch_bounds__(256, 4) void conv_kernel(const float* __restrict__ x,
                                                      const float* __restrict__ gT,
                                                      __hip_bfloat16* __restrict__ y) {
  const int bx    = blockIdx.x;        // 512 blocks: b(4) x chunk(32) x dg(4)
  const int b     = bx >> 7;
  const int rem   = bx & 127;
  const int chunk = rem >> 2;          // 0..31
  const int dg    = rem & 3;
  const int d     = dg * 256 + threadIdx.x;
  const int s0    = chunk * 64;
  const float* xb = x + b * (S_DIM * D_DIM) + d;
  short* yb       = (short*)y + b * (S_DIM * D_DIM) + d;

  float g[KTAPS];
#pragma unroll
  for (int k = 0; k < KTAPS; ++k) g[k] = gT[k * D_DIM + d];

  float hist[16];                      // x[s - 16 .. s - 1]
#pragma unroll
  for (int i = 0; i < 16; ++i) {
    int s = s0 - 16 + i;
    hist[i] = (s >= 0) ? xb[s * D_DIM] : 0.0f;
  }

  for (int t = 0; t < 4; ++t) {        // 4 sub-tiles of 16 outputs
    const int sb = s0 + t * 16;
    float cur[16];
#pragma unroll
    for (int i = 0; i < 16; ++i) cur[i] = xb[(sb + i) * D_DIM];
#pragma unroll
    for (int j = 0; j < 16; ++j) {
      float acc = 0.f;
#pragma unroll
      for (int k = 0; k < KTAPS; ++k) {
        const int idx = j - k;          // compile-time constant
        const float xv = (idx >= 0) ? cur[idx] : hist[16 + idx];
        acc = fmaf(g[k], xv, acc);
      }
      yb[(sb + j) * D_DIM] = f2bs(acc);
    }
#pragma unroll
    for (int i = 0; i < 16; ++i) hist[i] = cur[i];
  }
}

// ---------------------------------------------------------------------------
// Kernel 3: LayerNorm(D=1024) + exact GELU, bf16 row-major in -> Act in
// A-FRAGMENT ORDER. Block (128 thr) per row m; thread tid handles the 8
// consecutive k of one fragment slot: k0 = tid>>2, sub = tid&3,
// lane = sub*16 + (m&15)  ->  one contiguous 16 B store per thread.
// ---------------------------------------------------------------------------
__global__ __launch_bounds__(128) void ln_gelu_kernel(const __hip_bfloat16* __restrict__ y,
                                                      const float* __restrict__ w,
                                                      const float* __restrict__ bsh,
                                                      __hip_bfloat16* __restrict__ act) {
  __shared__ float red0[2];
  __shared__ float red1[2];
  const int row = blockIdx.x;          // m: 0..8191
  const int tid = threadIdx.x;         // 0..127
  const int lane = tid & 63, wid = tid >> 6;
  const int kb = tid * 8;

  const bf16x8 s8 = *(const bf16x8*)((const short*)y + (size_t)row * D_DIM + kb);
  float v[8];
#pragma unroll
  for (int j = 0; j < 8; ++j) v[j] = bs2f(s8[j]);

  float s = 0.f;
#pragma unroll
  for (int j = 0; j < 8; ++j) s += v[j];
  s += __shfl_xor(s, 1);  s += __shfl_xor(s, 2);  s += __shfl_xor(s, 4);
  s += __shfl_xor(s, 8);  s += __shfl_xor(s, 16); s += __shfl_xor(s, 32);
  if (lane == 0) red0[wid] = s;
  __syncthreads();
  const float mu = (red0[0] + red0[1]) * (1.0f / D_DIM);

  float sq = 0.f;
#pragma unroll
  for (int j = 0; j < 8; ++j) { float t = v[j] - mu; sq = fmaf(t, t, sq); }
  sq += __shfl_xor(sq, 1);  sq += __shfl_xor(sq, 2);  sq += __shfl_xor(sq, 4);
  sq += __shfl_xor(sq, 8);  sq += __shfl_xor(sq, 16); sq += __shfl_xor(sq, 32);
  if (lane == 0) red1[wid] = sq;
  __syncthreads();
  const float var = (red1[0] + red1[1]) * (1.0f / D_DIM);
  const float inv = rsqrtf(var + 1e-5f);

  const float4 w0 = *(const float4*)&w[kb];
  const float4 w1 = *(const float4*)&w[kb + 4];
  const float4 b0 = *(const float4*)&bsh[kb];
  const float4 b1 = *(const float4*)&bsh[kb + 4];
  const float wv[8] = {w0.x, w0.y, w0.z, w0.w, w1.x, w1.y, w1.z, w1.w};
  const float bv[8] = {b0.x, b0.y, b0.z, b0.w, b1.x, b1.y, b1.z, b1.w};
  bf16x8 o;
#pragma unroll
  for (int j = 0; j < 8; ++j) {
    float t = (v[j] - mu) * inv * wv[j] + bv[j];
    float ge = 0.5f * t * (1.f + erff(t * 0.70710678118654752f));  // exact gelu
    o[j] = f2bs(ge);
  }
  // fragment-order address
  const int p    = row >> 4;
  const int k0   = tid >> 2;                  // kb/32
  const int sub  = tid & 3;                   // (kb>>3)&3
  const int flane = sub * 16 + (row & 15);
  const size_t f = (((size_t)(p * 32 + k0) * 64) + flane) * 8;
  *(bf16x8*)((short*)act + f) = o;
}

// ---------------------------------------------------------------------------
// Kernel 4: out = x + Act @ W^T + b_out.  LDS-FREE fragment-direct MFMA GEMM.
// Both operands pre-stored in fragment order -> every fragment load is one
// coalesced 16B/lane global load (plain VMEM, no DMA, no barriers; compiler
// pipelines with fine vmcnt). Block = 1 wave, tile 64x64, 2048 blocks.
// n-major block id: mt64 = id&127 -> blocks sharing an A-panel get id%8 ==
// mt64%8, i.e. the same XCD under round-robin dispatch -> A stays in that
// XCD's L2 (read once from HBM). B (2 MB) replicates in every L2.
// C/D: col = lane&15, row = (lane>>4)*4 + reg.
// ---------------------------------------------------------------------------
__global__ __launch_bounds__(64, 2) void gemm_kernel(const __hip_bfloat16* __restrict__ Actf,
                                                     const __hip_bfloat16* __restrict__ Wbf,
                                                     const float* __restrict__ x,
                                                     const float* __restrict__ bout,
                                                     float* __restrict__ out) {
  const int lane = threadIdx.x;
  const int mt64 = blockIdx.x & 127;   // 8192/64
  const int nt64 = blockIdx.x >> 7;    // 1024/64
  const int l16  = lane & 15;
  const int kq   = lane >> 4;

  // panel stride = 32 k-blocks * 512 shorts = 16384 shorts
  const short* Af = (const short*)Actf + ((size_t)mt64 * 4) * 16384 + lane * 8;
  const short* Bf = (const short*)Wbf  + ((size_t)nt64 * 4) * 16384 + lane * 8;

  f32x4 acc[4][4];
#pragma unroll
  for (int mt = 0; mt < 4; ++mt)
#pragma unroll
    for (int nt = 0; nt < 4; ++nt) acc[mt][nt] = (f32x4){0.f, 0.f, 0.f, 0.f};

#pragma unroll 2
  for (int k0 = 0; k0 < 32; ++k0) {
    bf16x8 a[4], b[4];
#pragma unroll
    for (int mt = 0; mt < 4; ++mt)
      a[mt] = *(const bf16x8*)(Af + ((size_t)(mt * 32 + k0) << 9));
#pragma unroll
    for (int nt = 0; nt < 4; ++nt)
      b[nt] = *(const bf16x8*)(Bf + ((size_t)(nt * 32 + k0) << 9));
#pragma unroll
    for (int mt = 0; mt < 4; ++mt)
#pragma unroll
      for (int nt = 0; nt < 4; ++nt)
        acc[mt][nt] = __builtin_amdgcn_mfma_f32_16x16x32_bf16(a[mt], b[nt], acc[mt][nt], 0, 0, 0);
  }

  const int r0 = kq * 4;
#pragma unroll
  for (int mt = 0; mt < 4; ++mt) {
    const int row = mt64 * 64 + mt * 16 + r0;
#pragma unroll
    for (int nt = 0; nt < 4; ++nt) {
      const int col = nt64 * 64 + nt * 16 + l16;
      const float bo = bout[col];
#pragma unroll
      for (int r = 0; r < 4; ++r) {
        const int idx = (row + r) * D_DIM + col;
        out[idx] = x[idx] + acc[mt][nt][r] + bo;
      }
    }
  }
}

// ---------------------------------------------------------------------------
extern "C" void kernel_launch(void* const* d_in, const int* in_sizes, int n_in,
                              void* d_out, int out_size, void* d_ws, size_t ws_size,
                              hipStream_t stream) {
  const float* x    = (const float*)d_in[0];
  const float* A    = (const float*)d_in[1];
  const float* Bm   = (const float*)d_in[2];
  const float* Cm   = (const float*)d_in[3];
  const float* Dm   = (const float*)d_in[4];
  const float* lnw  = (const float*)d_in[5];
  const float* lnb  = (const float*)d_in[6];
  const float* Wout = (const float*)d_in[7];
  const float* bout = (const float*)d_in[8];
  float* out = (float*)d_out;

  char* ws = (char*)d_ws;
  float* gT            = (float*)ws;                        // 16*1024*4   = 64 KB
  __hip_bfloat16* Wbf  = (__hip_bfloat16*)(ws + 262144);    // 2 MB, frag order
  __hip_bfloat16* Actf = (__hip_bfloat16*)(ws + 2359296);   // 16.75 MB, frag order
  __hip_bfloat16* ybf  = (__hip_bfloat16*)(ws + 19136512);  // 16.75 MB, row-major

  setup_kernel<<<4160, 256, 0, stream>>>(Wout, Wbf, A, Bm, Cm, Dm, gT);
  conv_kernel<<<512, 256, 0, stream>>>(x, gT, ybf);
  ln_gelu_kernel<<<8192, 128, 0, stream>>>(ybf, lnw, lnb, Actf);
  gemm_kernel<<<2048, 64, 0, stream>>>(Actf, Wbf, x, bout, out);
}

// Round 10
// 150.808 us; speedup vs baseline: 1.1654x; 1.1654x over previous
//
#include <hip/hip_runtime.h>
#include <hip/hip_bf16.h>

#define D_DIM 1024
#define S_DIM 2048
#define B_DIM 4
#define KTAPS 16

typedef short bf16x8 __attribute__((ext_vector_type(8)));
typedef float f32x4 __attribute__((ext_vector_type(4)));

// async global->LDS, 16B per lane (global_load_lds_dwordx4)
#define GLOAD16(gptr, lptr) \
  __builtin_amdgcn_global_load_lds((const __attribute__((address_space(1))) unsigned int*)(gptr), \
                                   (__attribute__((address_space(3))) unsigned int*)(lptr), 16, 0, 0)

static __device__ __forceinline__ short f2bs(float f) {
  __hip_bfloat16 h = __float2bfloat16(f);
  return *reinterpret_cast<short*>(&h);
}

// ---------------------------------------------------------------------------
// Kernel 1 (merged setup): blocks [0,4096) cast W_out to bf16 (row-major);
// blocks [4096,4160) compute impulse response g_k[d] = C_d.A_d^k.B_d
// (Dm folded into tap 0).
// ---------------------------------------------------------------------------
__global__ void setup_kernel(const float* __restrict__ W, __hip_bfloat16* __restrict__ Wb,
                             const float* __restrict__ A, const float* __restrict__ Bm,
                             const float* __restrict__ Cm, const float* __restrict__ Dm,
                             float* __restrict__ gT) {
  if (blockIdx.x < 4096) {
    int i = blockIdx.x * 256 + threadIdx.x;
    Wb[i] = __float2bfloat16(W[i]);
    return;
  }
  const int gb   = blockIdx.x - 4096;  // 0..63
  const int wid  = threadIdx.x >> 6;   // 0..3
  const int lane = threadIdx.x & 63;
  const int sub  = lane >> 4;          // 0..3 (channel within wave)
  const int n    = lane & 15;          // state index
  const int d    = gb * 16 + wid * 4 + sub;
  float Ar[16];
#pragma unroll
  for (int m = 0; m < 16; ++m) Ar[m] = A[d * 256 + n * 16 + m];
  float v = Bm[d * 16 + n];
  const float c   = Cm[d * 16 + n];
  const float dmv = Dm[d];
  const int base  = sub << 4;
  for (int k = 0; k < KTAPS; ++k) {
    float dot = c * v;
    dot += __shfl_xor(dot, 1);
    dot += __shfl_xor(dot, 2);
    dot += __shfl_xor(dot, 4);
    dot += __shfl_xor(dot, 8);
    if (k == 0) dot += dmv;            // fold the D x_t skip term into tap 0
    if (n == 0) gT[k * D_DIM + d] = dot;
    float nv = 0.f;
#pragma unroll
    for (int m = 0; m < 16; ++m) nv = fmaf(Ar[m], __shfl(v, base + m), nv);
    v = nv;
  }
}

// ---------------------------------------------------------------------------
// Kernel 2 (fused): conv(16 taps) + LayerNorm + exact GELU -> Act (bf16,
// row-major). Block = 4 consecutive rows, 256 threads, thread owns 4 d-cols.
// x window (19 rows x float4) in registers, g streamed k-outer (low VGPR).
// All 4 rows' LN partial sums go through ONE barrier. Eliminates the ybf
// intermediate (33.5 MB HBM round-trip) of the split version.
// ---------------------------------------------------------------------------
__global__ __launch_bounds__(256) void convln_kernel(const float* __restrict__ x,
                                                     const float* __restrict__ gT,
                                                     const float* __restrict__ lnw,
                                                     const float* __restrict__ lnb,
                                                     __hip_bfloat16* __restrict__ act) {
  __shared__ float redS[16];   // [j*4 + wid]
  __shared__ float redQ[16];
  const int m0  = blockIdx.x * 4;      // global row (0..8191)
  const int b   = m0 >> 11;            // batch
  const int s0  = m0 & 2047;           // seq pos of row j=0
  const int tid = threadIdx.x;
  const int lane = tid & 63, wid = tid >> 6;
  const int d0  = tid * 4;
  const float* xb = x + ((size_t)b * S_DIM) * D_DIM + d0;

  // x window: w[i] = x[s0-15+i], i=0..18 (zero for s<0)
  f32x4 w[19];
#pragma unroll
  for (int i = 0; i < 19; ++i) {
    const int s = s0 - 15 + i;
    w[i] = (s >= 0) ? *(const f32x4*)(xb + (size_t)s * D_DIM) : (f32x4){0.f, 0.f, 0.f, 0.f};
  }

  // conv: 4 rows, k-outer (one g float4 live at a time)
  f32x4 a[4] = {(f32x4){0,0,0,0}, (f32x4){0,0,0,0}, (f32x4){0,0,0,0}, (f32x4){0,0,0,0}};
#pragma unroll
  for (int k = 0; k < KTAPS; ++k) {
    const f32x4 g4 = *(const f32x4*)(gT + k * D_DIM + d0);
#pragma unroll
    for (int j = 0; j < 4; ++j) {
      const f32x4 xv = w[15 + j - k];
#pragma unroll
      for (int c = 0; c < 4; ++c) a[j][c] = fmaf(g4[c], xv[c], a[j][c]);
    }
  }

  // LN partial sums for all 4 rows -> one barrier
#pragma unroll
  for (int j = 0; j < 4; ++j) {
    float s = a[j][0] + a[j][1] + a[j][2] + a[j][3];
    float q = a[j][0]*a[j][0] + a[j][1]*a[j][1] + a[j][2]*a[j][2] + a[j][3]*a[j][3];
    s += __shfl_xor(s, 1);  s += __shfl_xor(s, 2);  s += __shfl_xor(s, 4);
    s += __shfl_xor(s, 8);  s += __shfl_xor(s, 16); s += __shfl_xor(s, 32);
    q += __shfl_xor(q, 1);  q += __shfl_xor(q, 2);  q += __shfl_xor(q, 4);
    q += __shfl_xor(q, 8);  q += __shfl_xor(q, 16); q += __shfl_xor(q, 32);
    if (lane == 0) { redS[j * 4 + wid] = s; redQ[j * 4 + wid] = q; }
  }
  __syncthreads();

  const f32x4 w4 = *(const f32x4*)&lnw[d0];
  const f32x4 b4 = *(const f32x4*)&lnb[d0];
#pragma unroll
  for (int j = 0; j < 4; ++j) {
    const float sum = redS[j*4+0] + redS[j*4+1] + redS[j*4+2] + redS[j*4+3];
    const float sq  = redQ[j*4+0] + redQ[j*4+1] + redQ[j*4+2] + redQ[j*4+3];
    const float mu  = sum * (1.0f / D_DIM);
    const float var = sq * (1.0f / D_DIM) - mu * mu;
    const float inv = rsqrtf(var + 1e-5f);
    short4 o;
    short* op = &o.x;
#pragma unroll
    for (int c = 0; c < 4; ++c) {
      float t = (a[j][c] - mu) * inv * w4[c] + b4[c];
      float ge = 0.5f * t * (1.f + erff(t * 0.70710678118654752f));  // exact gelu
      op[c] = f2bs(ge);
    }
    *(short4*)((short*)act + (size_t)(m0 + j) * D_DIM + d0) = o;
  }
}

// ---------------------------------------------------------------------------
// Kernel 3: out = x + Act @ W^T + b_out.  R5's verified-best LDS MFMA GEMM.
// 128x128 block tile, BK=128 (8 K-iters), global_load_lds width=16 staging,
// XOR-swizzled LDS layout: 16B chunk c of row r at slot (c ^ (r&7)) ->
// fragment reads are 2-way (free). 4 waves (2x2), wave = 64x64 via 4x4 MFMA.
// A-frag: lane holds Act[m = l16][koff + j],  koff = (lane>>4)*8
// B-frag: lane holds W  [n = l16][koff + j]   (W row = out col)
// C/D   : col = lane&15, row = (lane>>4)*4 + reg
// ---------------------------------------------------------------------------
__global__ __launch_bounds__(256, 2) void gemm_kernel(const __hip_bfloat16* __restrict__ Act,
                                                      const __hip_bfloat16* __restrict__ Wb,
                                                      const float* __restrict__ x,
                                                      const float* __restrict__ bout,
                                                      float* __restrict__ out) {
  __shared__ short Al[128 * 128];  // 32 KB
  __shared__ short Bl[128 * 128];  // 32 KB
  const int tid  = threadIdx.x;
  const int lane = tid & 63;
  const int wave = tid >> 6;
  const int mBase = blockIdx.x * 128;
  const int nBase = blockIdx.y * 128;
  const int wm = (wave & 1) * 64;
  const int wn = (wave >> 1) * 64;
  const int l16 = lane & 15;
  const int kq  = lane >> 4;          // 0..3 k-quad

  // staging: thread t -> row (tid>>4) (+16/round, 8 rounds); 16 chunks/row,
  // this thread's LDS slot is (tid&15) => it fetches global chunk slot^(row&7)
  const int srow = tid >> 4;                       // 0..15
  const int cg   = (tid & 15) ^ (srow & 7);        // global 16B chunk fetched
  const short* Ag = (const short*)Act + (mBase + srow) * D_DIM + cg * 8;
  const short* Bg = (const short*)Wb  + (nBase + srow) * D_DIM + cg * 8;
  short* Als = Al + tid * 8;   // round r adds 2048 shorts (16 rows)
  short* Bls = Bl + tid * 8;

  f32x4 acc[4][4];
#pragma unroll
  for (int mt = 0; mt < 4; ++mt)
#pragma unroll
    for (int nt = 0; nt < 4; ++nt) acc[mt][nt] = (f32x4){0.f, 0.f, 0.f, 0.f};

  for (int k0 = 0; k0 < D_DIM; k0 += 128) {
    __syncthreads();                       // readers of previous tile done
#pragma unroll
    for (int r = 0; r < 8; ++r) {
      GLOAD16(Ag + r * 16 * D_DIM + k0, Als + r * 2048);
      GLOAD16(Bg + r * 16 * D_DIM + k0, Bls + r * 2048);
    }
    __syncthreads();                       // staged data visible
#pragma unroll
    for (int kk = 0; kk < 128; kk += 32) {
      bf16x8 af[4], bfr[4];
      const int cgr = (kk >> 3) + kq;      // global chunk this fragment needs
#pragma unroll
      for (int mt = 0; mt < 4; ++mt) {
        const int r = wm + mt * 16 + l16;
        af[mt] = *(const bf16x8*)&Al[r * 128 + ((cgr ^ (r & 7)) << 3)];
      }
#pragma unroll
      for (int nt = 0; nt < 4; ++nt) {
        const int r = wn + nt * 16 + l16;
        bfr[nt] = *(const bf16x8*)&Bl[r * 128 + ((cgr ^ (r & 7)) << 3)];
      }
#pragma unroll
      for (int mt = 0; mt < 4; ++mt)
#pragma unroll
        for (int nt = 0; nt < 4; ++nt)
          acc[mt][nt] = __builtin_amdgcn_mfma_f32_16x16x32_bf16(af[mt], bfr[nt], acc[mt][nt], 0, 0, 0);
    }
  }

  const int r0 = kq * 4;
#pragma unroll
  for (int mt = 0; mt < 4; ++mt) {
    const int row = mBase + wm + mt * 16 + r0;
#pragma unroll
    for (int nt = 0; nt < 4; ++nt) {
      const int col = nBase + wn + nt * 16 + l16;
      const float bo = bout[col];
#pragma unroll
      for (int r = 0; r < 4; ++r) {
        const int idx = (row + r) * D_DIM + col;
        out[idx] = x[idx] + acc[mt][nt][r] + bo;
      }
    }
  }
}

// ---------------------------------------------------------------------------
extern "C" void kernel_launch(void* const* d_in, const int* in_sizes, int n_in,
                              void* d_out, int out_size, void* d_ws, size_t ws_size,
                              hipStream_t stream) {
  const float* x    = (const float*)d_in[0];
  const float* A    = (const float*)d_in[1];
  const float* Bm   = (const float*)d_in[2];
  const float* Cm   = (const float*)d_in[3];
  const float* Dm   = (const float*)d_in[4];
  const float* lnw  = (const float*)d_in[5];
  const float* lnb  = (const float*)d_in[6];
  const float* Wout = (const float*)d_in[7];
  const float* bout = (const float*)d_in[8];
  float* out = (float*)d_out;

  char* ws = (char*)d_ws;
  float* gT            = (float*)ws;                        // 16*1024*4   = 64 KB
  __hip_bfloat16* Wb   = (__hip_bfloat16*)(ws + 262144);    // 1024*1024*2 = 2 MB, row-major
  __hip_bfloat16* Act  = (__hip_bfloat16*)(ws + 2359296);   // 8192*1024*2 = 16.75 MB, row-major

  setup_kernel<<<4160, 256, 0, stream>>>(Wout, Wb, A, Bm, Cm, Dm, gT);
  convln_kernel<<<2048, 256, 0, stream>>>(x, gT, lnw, lnb, Act);
  gemm_kernel<<<dim3(64, 8), 256, 0, stream>>>(Act, Wb, x, bout, out);
}